// Round 3
// baseline (153.006 us; speedup 1.0000x reference)
//
#include <hip/hip_runtime.h>

#define NBINS 64
#define NGRAPH 64
#define SPTS 1024
#define HID 256

// -------- Kernel 1: per-graph pairwise distance histogram --------
// Full symmetric matrix (i over a 128-row tile, j over all 1024 split in
// halves across waves). Diagonal + double-count corrected in kernel 2.
__global__ __launch_bounds__(256) void hist_kernel(const float* __restrict__ pos,
                                                   unsigned int* __restrict__ hist) {
  int g    = blockIdx.x >> 3;   // graph id
  int tile = blockIdx.x & 7;    // i-tile of 128 rows
  __shared__ float4 pl[SPTS];               // 16 KB staged positions
  __shared__ unsigned int h[4 * NBINS];     // per-wave private histograms
  int t = threadIdx.x;

  for (int k = t; k < 4 * NBINS; k += 256) h[k] = 0u;

  const float* gp = pos + (size_t)g * SPTS * 3;
  for (int r = t; r < SPTS; r += 256) {
    pl[r] = make_float4(gp[3 * r], gp[3 * r + 1], gp[3 * r + 2], 0.0f);
  }
  __syncthreads();

  int i     = tile * 128 + (t & 127);
  int jbase = (t >> 7) * 512;       // waves 0,1 -> j[0,512), waves 2,3 -> j[512,1024)
  float4 pi = pl[i];
  unsigned int* hw = h + (t >> 6) * NBINS;  // per-wave histogram
  const float scale = 64.0f / 25.0f;

  #pragma unroll 4
  for (int jj = 0; jj < 512; ++jj) {
    float4 pj = pl[jbase + jj];     // wave-uniform broadcast read
    float dx = pi.x - pj.x;
    float dy = pi.y - pj.y;
    float dz = pi.z - pj.z;
    float d2 = dx * dx + dy * dy + dz * dz;
    float d  = sqrtf(d2);
    if (d <= 25.0f) {
      int bin = (int)(d * scale);
      bin = bin > 63 ? 63 : bin;
      atomicAdd(&hw[bin], 1u);      // ds_add_u32, per-wave private
    }
  }
  __syncthreads();

  for (int k = t; k < NBINS; k += 256) {
    unsigned int v = h[k] + h[NBINS + k] + h[2 * NBINS + k] + h[3 * NBINS + k];
    if (v) atomicAdd(&hist[g * NBINS + k], v);
  }
}

// -------- Kernel 2: correction + normalization + 2-layer MLP --------
__global__ __launch_bounds__(256) void mlp_kernel(const unsigned int* __restrict__ hist,
                                                  const float* __restrict__ W1,
                                                  const float* __restrict__ b1,
                                                  const float* __restrict__ W2,
                                                  const float* __restrict__ b2,
                                                  float* __restrict__ out) {
  int g = blockIdx.x;
  int t = threadIdx.x;
  __shared__ float hn[NBINS];
  __shared__ float h1[HID];
  __shared__ float ssum;

  if (t < NBINS) {
    unsigned int c = hist[g * NBINS + t];
    unsigned int corr = (t == 0) ? (c - SPTS) : c;  // remove diagonal (dist=0)
    hn[t] = 0.5f * (float)corr;                     // undo symmetric double count
  }
  __syncthreads();
  if (t == 0) {
    float s = 0.0f;
    for (int k = 0; k < NBINS; ++k) s += hn[k];     // exact: halves of ints < 2^23
    ssum = s + 1e-8f;
  }
  __syncthreads();
  if (t < NBINS) hn[t] = hn[t] / ssum;
  __syncthreads();

  // layer 1: h1 = silu(hn @ W1^T + b1), thread t -> output channel t
  float acc = b1[t];
  #pragma unroll
  for (int k = 0; k < NBINS; ++k) acc += hn[k] * W1[t * NBINS + k];
  float sig = 1.0f / (1.0f + expf(-acc));
  h1[t] = acc * sig;
  __syncthreads();

  // layer 2: out = h1 @ W2^T + b2
  float acc2 = b2[t];
  #pragma unroll 8
  for (int k = 0; k < HID; ++k) acc2 += h1[k] * W2[t * HID + k];
  out[g * HID + t] = acc2;
}

extern "C" void kernel_launch(void* const* d_in, const int* in_sizes, int n_in,
                              void* d_out, int out_size, void* d_ws, size_t ws_size,
                              hipStream_t stream) {
  const float* pos = (const float*)d_in[0];
  const float* W1  = (const float*)d_in[1];
  const float* b1  = (const float*)d_in[2];
  const float* W2  = (const float*)d_in[3];
  const float* b2  = (const float*)d_in[4];
  // d_in[5] = batch ids: unused (contiguous equal-size segments by construction)

  unsigned int* hist = (unsigned int*)d_ws;   // 64*64*4 = 16 KB scratch
  hipMemsetAsync(hist, 0, NGRAPH * NBINS * sizeof(unsigned int), stream);

  hipLaunchKernelGGL(hist_kernel, dim3(NGRAPH * 8), dim3(256), 0, stream, pos, hist);
  hipLaunchKernelGGL(mlp_kernel, dim3(NGRAPH), dim3(256), 0, stream,
                     hist, W1, b1, W2, b2, (float*)d_out);
}

// Round 4
// 108.459 us; speedup vs baseline: 1.4107x; 1.4107x over previous
//
#include <hip/hip_runtime.h>

#define NBINS 64
#define NGRAPH 64
#define SPTS 1024
#define HID 256
#define JCH 128           // j-chunk staged in LDS
#define NJCH 8            // 1024 / 128
#define NICH 2            // i-chunks of 512 (2 i's per thread x 256 threads)
#define BPG (NICH * NJCH) // blocks per graph = 16

// -------- Kernel 1: per-graph pairwise distance histogram (partials) --------
// Full symmetric sweep; each block: 512 i's (2/thread) x 128 staged j's.
// Writes a private 64-bin partial per block (no global atomics, no memset).
__global__ __launch_bounds__(256) void hist_kernel(const float* __restrict__ pos,
                                                   unsigned int* __restrict__ partial) {
  int bid = blockIdx.x;
  int jc  = bid & (NJCH - 1);
  int ic  = (bid >> 3) & (NICH - 1);
  int g   = bid >> 4;
  int t   = threadIdx.x;

  __shared__ float4 pl[JCH];            // 2 KB staged j-positions
  __shared__ unsigned int h[4 * NBINS]; // 1 KB per-wave histograms

  h[t] = 0u;
  if (t < JCH) {
    const float* gp = pos + (size_t)((g << 10) + (jc << 7) + t) * 3;
    pl[t] = make_float4(gp[0], gp[1], gp[2], 0.0f);
  }

  int ibase = (g << 10) + (ic << 9);
  const float* ip0 = pos + (size_t)(ibase + t) * 3;
  const float* ip1 = pos + (size_t)(ibase + 256 + t) * 3;
  float x0 = ip0[0], y0 = ip0[1], z0 = ip0[2];
  float x1 = ip1[0], y1 = ip1[1], z1 = ip1[2];
  __syncthreads();

  unsigned int* hw = h + (t >> 6) * NBINS;
  const float s2 = 6.5536f; // (64/25)^2

  #pragma unroll 4
  for (int jj = 0; jj < JCH; ++jj) {
    float4 pj = pl[jj];                 // wave-uniform broadcast ds_read_b128
    float dxa = x0 - pj.x, dya = y0 - pj.y, dza = z0 - pj.z;
    float d2a = dxa * dxa + dya * dya + dza * dza;
    float dxb = x1 - pj.x, dyb = y1 - pj.y, dzb = z1 - pj.z;
    float d2b = dxb * dxb + dyb * dyb + dzb * dzb;
    if (d2a <= 625.0f) {
      int ba = (int)__builtin_amdgcn_sqrtf(d2a * s2); // raw v_sqrt_f32
      atomicAdd(&hw[ba > 63 ? 63 : ba], 1u);
    }
    if (d2b <= 625.0f) {
      int bb = (int)__builtin_amdgcn_sqrtf(d2b * s2);
      atomicAdd(&hw[bb > 63 ? 63 : bb], 1u);
    }
  }
  __syncthreads();

  if (t < NBINS) {
    partial[(size_t)bid * NBINS + t] =
        h[t] + h[NBINS + t] + h[2 * NBINS + t] + h[3 * NBINS + t];
  }
}

// -------- Kernel 2: partial-sum + correction + normalization + MLP --------
__global__ __launch_bounds__(256) void mlp_kernel(const unsigned int* __restrict__ partial,
                                                  const float* __restrict__ W1,
                                                  const float* __restrict__ b1,
                                                  const float* __restrict__ W2,
                                                  const float* __restrict__ b2,
                                                  float* __restrict__ out) {
  int g = blockIdx.x;
  int t = threadIdx.x;
  __shared__ float hn[NBINS];
  __shared__ float h1[HID];

  if (t < NBINS) { // wave 0 only
    unsigned int s = 0u;
    #pragma unroll
    for (int p = 0; p < BPG; ++p) s += partial[(size_t)(g * BPG + p) * NBINS + t];
    // remove diagonal (i==j, dist 0 -> bin 0), undo symmetric double count
    float hv = 0.5f * (float)(t == 0 ? s - SPTS : s);
    float tot = hv; // exact: multiples of 0.5, total < 2^23 -> order-free
    #pragma unroll
    for (int m = 1; m < 64; m <<= 1) tot += __shfl_xor(tot, m, 64);
    hn[t] = hv / (tot + 1e-8f);
  }
  __syncthreads();

  // layer 1: h1 = silu(hn @ W1^T + b1), thread t -> channel t
  float acc = b1[t];
  #pragma unroll
  for (int k = 0; k < NBINS; ++k) acc += hn[k] * W1[t * NBINS + k];
  float sig = 1.0f / (1.0f + expf(-acc));
  h1[t] = acc * sig;
  __syncthreads();

  // layer 2: out = h1 @ W2^T + b2
  float acc2 = b2[t];
  #pragma unroll 8
  for (int k = 0; k < HID; ++k) acc2 += h1[k] * W2[t * HID + k];
  out[g * HID + t] = acc2;
}

extern "C" void kernel_launch(void* const* d_in, const int* in_sizes, int n_in,
                              void* d_out, int out_size, void* d_ws, size_t ws_size,
                              hipStream_t stream) {
  const float* pos = (const float*)d_in[0];
  const float* W1  = (const float*)d_in[1];
  const float* b1  = (const float*)d_in[2];
  const float* W2  = (const float*)d_in[3];
  const float* b2  = (const float*)d_in[4];
  // d_in[5] = batch ids: unused (contiguous equal-size segments by construction)

  unsigned int* partial = (unsigned int*)d_ws; // 1024 * 64 * 4 = 256 KB scratch

  hipLaunchKernelGGL(hist_kernel, dim3(NGRAPH * BPG), dim3(256), 0, stream, pos, partial);
  hipLaunchKernelGGL(mlp_kernel, dim3(NGRAPH), dim3(256), 0, stream,
                     partial, W1, b1, W2, b2, (float*)d_out);
}

// Round 5
// 85.453 us; speedup vs baseline: 1.7905x; 1.2692x over previous
//
#include <hip/hip_runtime.h>

#define NBINS 64
#define NGRAPH 64
#define SPTS 1024
#define HID 256
#define TILE 128
#define NTILE 8            // 1024 / 128
#define NPAIR 36           // ti<=tj tile pairs
#define BPG NPAIR          // hist blocks per graph

// triangular tile-pair lookup (p -> (ti,tj), ti<=tj)
__device__ __constant__ unsigned char ti_tab[NPAIR] = {
  0,0,0,0,0,0,0,0, 1,1,1,1,1,1,1, 2,2,2,2,2,2, 3,3,3,3,3, 4,4,4,4, 5,5,5, 6,6, 7};
__device__ __constant__ unsigned char tj_tab[NPAIR] = {
  0,1,2,3,4,5,6,7, 1,2,3,4,5,6,7, 2,3,4,5,6,7, 3,4,5,6,7, 4,5,6,7, 5,6,7, 6,7, 7};

// -------- Kernel 1: triangular tiled pairwise-distance histogram --------
// Block = (graph, tile-pair). Each unordered i<j pair counted exactly once:
// off-diagonal tiles count all 128x128 combos, diagonal tiles predicate
// i_local < j_local. No self-pairs, no double count -> no correction needed.
__global__ __launch_bounds__(256) void hist_kernel(const float* __restrict__ pos,
                                                   unsigned int* __restrict__ partial) {
  int bid = blockIdx.x;
  int g   = bid / NPAIR;
  int p   = bid - g * NPAIR;
  int ti  = ti_tab[p];
  int tj  = tj_tab[p];
  bool offdiag = (ti != tj);
  int t = threadIdx.x;

  __shared__ float4 pli[TILE];              // 2 KB i-tile
  __shared__ float4 plj[TILE];              // 2 KB j-tile
  __shared__ unsigned int h4[NBINS * 4];    // 1 KB, 4-way bank-spread sub-hists

  h4[t] = 0u;
  {
    int base = (g << 10) + ((t < TILE ? ti : tj) << 7) + (t & (TILE - 1));
    const float* gp = pos + (size_t)base * 3;
    float4 v = make_float4(gp[0], gp[1], gp[2], 0.0f);
    if (t < TILE) pli[t] = v; else plj[t - TILE] = v;
  }
  __syncthreads();

  // thread t: i-pair (2*(t&63), 2*(t&63)+1), j-quarter (t>>6)*32 (wave-uniform)
  int il0 = (t & 63) * 2;
  int il1 = il0 + 1;
  float4 pa = pli[il0];
  float4 pb = pli[il1];
  int jbase = (t >> 6) * 32;
  unsigned int sub = t & 3;
  const float s2 = 6.5536f; // (64/25)^2

  #pragma unroll 4
  for (int jj = 0; jj < 32; ++jj) {
    int jl = jbase + jj;
    float4 pj = plj[jl];                    // wave-uniform broadcast ds_read_b128
    float dxa = pa.x - pj.x, dya = pa.y - pj.y, dza = pa.z - pj.z;
    float d2a = dxa * dxa + dya * dya + dza * dza;
    float dxb = pb.x - pj.x, dyb = pb.y - pj.y, dzb = pb.z - pj.z;
    float d2b = dxb * dxb + dyb * dyb + dzb * dzb;
    if (d2a <= 625.0f && (offdiag || il0 < jl)) {
      int ba = (int)__builtin_amdgcn_sqrtf(d2a * s2);  // floor(d*2.56)
      atomicAdd(&h4[(ba > 63 ? 63 : ba) * 4 + sub], 1u);
    }
    if (d2b <= 625.0f && (offdiag || il1 < jl)) {
      int bb = (int)__builtin_amdgcn_sqrtf(d2b * s2);
      atomicAdd(&h4[(bb > 63 ? 63 : bb) * 4 + sub], 1u);
    }
  }
  __syncthreads();

  if (t < NBINS) {
    partial[(size_t)bid * NBINS + t] =
        h4[t * 4] + h4[t * 4 + 1] + h4[t * 4 + 2] + h4[t * 4 + 3];
  }
}

// -------- Kernel 2: partial-sum + normalize + 2-layer MLP --------
// Block = (graph, output-quarter). hist assembly + layer1 done redundantly
// per quarter (cheap); layer2 k-sliced across the 4 waves.
__global__ __launch_bounds__(256) void mlp_kernel(const unsigned int* __restrict__ partial,
                                                  const float* __restrict__ W1,
                                                  const float* __restrict__ b1,
                                                  const float* __restrict__ W2,
                                                  const float* __restrict__ b2,
                                                  float* __restrict__ out) {
  int g = blockIdx.x >> 2;
  int q = blockIdx.x & 3;
  int t = threadIdx.x;
  __shared__ float hn[NBINS];
  __shared__ float h1[HID];
  __shared__ float p2[4][NBINS];

  if (t < NBINS) { // wave 0: assemble histogram, normalize
    unsigned int s = 0u;
    const unsigned int* pp = partial + (size_t)g * BPG * NBINS + t;
    #pragma unroll
    for (int p = 0; p < BPG; ++p) s += pp[p * NBINS];
    float hv = (float)s;                 // exact: < 2^23
    float tot = hv;
    #pragma unroll
    for (int m = 1; m < 64; m <<= 1) tot += __shfl_xor(tot, m, 64);
    hn[t] = hv / (tot + 1e-8f);
  }
  __syncthreads();

  // layer 1: h1 = silu(hn @ W1^T + b1), thread t -> channel t (float4 row)
  {
    float acc = b1[t];
    const float4* w = (const float4*)(W1 + (size_t)t * NBINS);
    #pragma unroll
    for (int k = 0; k < NBINS / 4; ++k) {
      float4 wv = w[k];
      acc += hn[4 * k] * wv.x + hn[4 * k + 1] * wv.y +
             hn[4 * k + 2] * wv.z + hn[4 * k + 3] * wv.w;
    }
    float sig = 1.0f / (1.0f + expf(-acc));
    h1[t] = acc * sig;
  }
  __syncthreads();

  // layer 2: 64 outputs (quarter q), k sliced over 4 waves
  {
    int o  = (q << 6) + (t & 63);
    int ks = (t >> 6) << 6;              // 64-wide k-slice per wave
    float acc = 0.0f;
    const float4* w = (const float4*)(W2 + (size_t)o * HID + ks);
    #pragma unroll
    for (int k = 0; k < 16; ++k) {
      float4 wv = w[k];
      acc += h1[ks + 4 * k] * wv.x + h1[ks + 4 * k + 1] * wv.y +
             h1[ks + 4 * k + 2] * wv.z + h1[ks + 4 * k + 3] * wv.w;
    }
    p2[t >> 6][t & 63] = acc;
  }
  __syncthreads();

  if (t < 64) {
    int o = (q << 6) + t;
    out[(size_t)g * HID + o] = b2[o] + p2[0][t] + p2[1][t] + p2[2][t] + p2[3][t];
  }
}

extern "C" void kernel_launch(void* const* d_in, const int* in_sizes, int n_in,
                              void* d_out, int out_size, void* d_ws, size_t ws_size,
                              hipStream_t stream) {
  const float* pos = (const float*)d_in[0];
  const float* W1  = (const float*)d_in[1];
  const float* b1  = (const float*)d_in[2];
  const float* W2  = (const float*)d_in[3];
  const float* b2  = (const float*)d_in[4];
  // d_in[5] = batch ids: unused (contiguous equal-size segments by construction)

  unsigned int* partial = (unsigned int*)d_ws; // 2304 * 64 * 4 = 576 KB scratch

  hipLaunchKernelGGL(hist_kernel, dim3(NGRAPH * BPG), dim3(256), 0, stream, pos, partial);
  hipLaunchKernelGGL(mlp_kernel, dim3(NGRAPH * 4), dim3(256), 0, stream,
                     partial, W1, b1, W2, b2, (float*)d_out);
}

// Round 6
// 83.856 us; speedup vs baseline: 1.8246x; 1.0191x over previous
//
#include <hip/hip_runtime.h>

#define NBINS 64
#define NGRAPH 64
#define SPTS 1024
#define HID 256
#define TILE 128
#define NPAIR 36           // ti<=tj tile pairs
#define BPG NPAIR          // hist blocks per graph
#define NSUB 8             // sub-histograms per block

// triangular tile-pair lookup (p -> (ti,tj), ti<=tj)
__device__ __constant__ unsigned char ti_tab[NPAIR] = {
  0,0,0,0,0,0,0,0, 1,1,1,1,1,1,1, 2,2,2,2,2,2, 3,3,3,3,3, 4,4,4,4, 5,5,5, 6,6, 7};
__device__ __constant__ unsigned char tj_tab[NPAIR] = {
  0,1,2,3,4,5,6,7, 1,2,3,4,5,6,7, 2,3,4,5,6,7, 3,4,5,6,7, 4,5,6,7, 5,6,7, 6,7, 7};

// Inner pair loop. OFFDIAG hoists the i<j predicate out of 28/36 blocks.
// h8 layout bin*8+sub: disjoint bank sets per sub-group, ~2-way conflicts.
template <bool OFFDIAG>
__device__ __forceinline__ void pair_loop(const float4* __restrict__ plj,
                                          unsigned int* __restrict__ h8,
                                          float4 pa, float4 pb, int il0, int il1,
                                          int jbase, unsigned int sub) {
  const float s2 = 6.5536f; // (64/25)^2
  #pragma unroll 4
  for (int jj = 0; jj < 32; ++jj) {
    int jl = jbase + jj;
    float4 pj = plj[jl];                  // wave-uniform broadcast ds_read_b128
    float dxa = pa.x - pj.x, dya = pa.y - pj.y, dza = pa.z - pj.z;
    float d2a = dxa * dxa + dya * dya + dza * dza;
    float dxb = pb.x - pj.x, dyb = pb.y - pj.y, dzb = pb.z - pj.z;
    float d2b = dxb * dxb + dyb * dyb + dzb * dzb;
    if (d2a <= 625.0f && (OFFDIAG || il0 < jl)) {
      int ba = (int)__builtin_amdgcn_sqrtf(d2a * s2);  // floor(d*2.56)
      atomicAdd(&h8[(ba > 63 ? 63 : ba) * NSUB + sub], 1u);
    }
    if (d2b <= 625.0f && (OFFDIAG || il1 < jl)) {
      int bb = (int)__builtin_amdgcn_sqrtf(d2b * s2);
      atomicAdd(&h8[(bb > 63 ? 63 : bb) * NSUB + sub], 1u);
    }
  }
}

// -------- Kernel 1: triangular tiled pairwise-distance histogram --------
// Block = (graph, tile-pair). Each unordered i<j pair counted exactly once.
__global__ __launch_bounds__(256) void hist_kernel(const float* __restrict__ pos,
                                                   unsigned int* __restrict__ partial) {
  int bid = blockIdx.x;
  int g   = bid / NPAIR;
  int p   = bid - g * NPAIR;
  int ti  = ti_tab[p];
  int tj  = tj_tab[p];
  int t   = threadIdx.x;

  __shared__ float4 pli[TILE];               // 2 KB i-tile
  __shared__ float4 plj[TILE];               // 2 KB j-tile
  __shared__ unsigned int h8[NBINS * NSUB];  // 2 KB, 8-way sub-histograms

  h8[t] = 0u;
  h8[t + 256] = 0u;
  {
    int base = (g << 10) + ((t < TILE ? ti : tj) << 7) + (t & (TILE - 1));
    const float* gp = pos + (size_t)base * 3;
    float4 v = make_float4(gp[0], gp[1], gp[2], 0.0f);
    if (t < TILE) pli[t] = v; else plj[t - TILE] = v;
  }
  __syncthreads();

  // thread t: i-pair (2*(t&63), 2*(t&63)+1), j-quarter (t>>6)*32 (wave-uniform)
  int il0 = (t & 63) * 2;
  int il1 = il0 + 1;
  float4 pa = pli[il0];
  float4 pb = pli[il1];
  int jbase = (t >> 6) * 32;
  unsigned int sub = t & (NSUB - 1);

  if (ti != tj) pair_loop<true >(plj, h8, pa, pb, il0, il1, jbase, sub);
  else          pair_loop<false>(plj, h8, pa, pb, il0, il1, jbase, sub);
  __syncthreads();

  if (t < NBINS) {
    unsigned int s = 0u;
    #pragma unroll
    for (int k = 0; k < NSUB; ++k) s += h8[t * NSUB + k];
    partial[(size_t)bid * NBINS + t] = s;
  }
}

// -------- Kernel 2: partial-sum + normalize + 2-layer MLP --------
// Block = (graph, output-quarter). layer1 redundant per quarter (cheap);
// layer2 k-sliced across the 4 waves.
__global__ __launch_bounds__(256) void mlp_kernel(const unsigned int* __restrict__ partial,
                                                  const float* __restrict__ W1,
                                                  const float* __restrict__ b1,
                                                  const float* __restrict__ W2,
                                                  const float* __restrict__ b2,
                                                  float* __restrict__ out) {
  int g = blockIdx.x >> 2;
  int q = blockIdx.x & 3;
  int t = threadIdx.x;
  __shared__ float hn[NBINS];
  __shared__ float h1[HID];
  __shared__ float p2[4][NBINS];

  if (t < NBINS) { // wave 0: assemble histogram, normalize
    unsigned int s = 0u;
    const unsigned int* pp = partial + (size_t)g * BPG * NBINS + t;
    #pragma unroll
    for (int p = 0; p < BPG; ++p) s += pp[p * NBINS];
    float hv = (float)s;                 // exact: < 2^23
    float tot = hv;
    #pragma unroll
    for (int m = 1; m < 64; m <<= 1) tot += __shfl_xor(tot, m, 64);
    hn[t] = hv / (tot + 1e-8f);
  }
  __syncthreads();

  // layer 1: h1 = silu(hn @ W1^T + b1), thread t -> channel t (float4 row)
  {
    float acc = b1[t];
    const float4* w = (const float4*)(W1 + (size_t)t * NBINS);
    #pragma unroll
    for (int k = 0; k < NBINS / 4; ++k) {
      float4 wv = w[k];
      acc += hn[4 * k] * wv.x + hn[4 * k + 1] * wv.y +
             hn[4 * k + 2] * wv.z + hn[4 * k + 3] * wv.w;
    }
    float sig = 1.0f / (1.0f + expf(-acc));
    h1[t] = acc * sig;
  }
  __syncthreads();

  // layer 2: 64 outputs (quarter q), k sliced over 4 waves
  {
    int o  = (q << 6) + (t & 63);
    int ks = (t >> 6) << 6;              // 64-wide k-slice per wave
    float acc = 0.0f;
    const float4* w = (const float4*)(W2 + (size_t)o * HID + ks);
    #pragma unroll
    for (int k = 0; k < 16; ++k) {
      float4 wv = w[k];
      acc += h1[ks + 4 * k] * wv.x + h1[ks + 4 * k + 1] * wv.y +
             h1[ks + 4 * k + 2] * wv.z + h1[ks + 4 * k + 3] * wv.w;
    }
    p2[t >> 6][t & 63] = acc;
  }
  __syncthreads();

  if (t < 64) {
    int o = (q << 6) + t;
    out[(size_t)g * HID + o] = b2[o] + p2[0][t] + p2[1][t] + p2[2][t] + p2[3][t];
  }
}

extern "C" void kernel_launch(void* const* d_in, const int* in_sizes, int n_in,
                              void* d_out, int out_size, void* d_ws, size_t ws_size,
                              hipStream_t stream) {
  const float* pos = (const float*)d_in[0];
  const float* W1  = (const float*)d_in[1];
  const float* b1  = (const float*)d_in[2];
  const float* W2  = (const float*)d_in[3];
  const float* b2  = (const float*)d_in[4];
  // d_in[5] = batch ids: unused (contiguous equal-size segments by construction)

  unsigned int* partial = (unsigned int*)d_ws; // 2304 * 64 * 4 = 576 KB scratch

  hipLaunchKernelGGL(hist_kernel, dim3(NGRAPH * BPG), dim3(256), 0, stream, pos, partial);
  hipLaunchKernelGGL(mlp_kernel, dim3(NGRAPH * 4), dim3(256), 0, stream,
                     partial, W1, b1, W2, b2, (float*)d_out);
}